// Round 9
// baseline (262.922 us; speedup 1.0000x reference)
//
#include <hip/hip_runtime.h>
#include <math.h>

#define BATCH   64
#define CH      256
#define RCH     64
#define HW      3136          // 56*56 floats per plane
#define HWF4    784           // f4 per plane (3136/4)
#define NBLK    256           // one block per CU (cooperative co-residency)
#define NTHR    1024          // 16 waves/block -> 4 waves/EU at 1 block/CU
#define PPB     64            // planes per block
#define PPW     4             // planes per wave (64 planes / 16 waves)
#define RSTR    6             // strides held in fp16 REGISTERS (48 VGPR/wave)
#define LSTR    4             // strides held in fp16 LDS (128 KiB)

typedef float  f4  __attribute__((ext_vector_type(4)));
typedef __fp16 hf2 __attribute__((ext_vector_type(2)));   // cvt_pkrtz's type

union H4 { uint2 u; hf2 h[2]; };

// Monotonic grid-barrier counter. Never reset: blocks release at the next
// multiple of NBLK above their arrival ticket, so it climbs across replays.
__device__ int g_ctr = 0;

// Lesson R4-R8: VGPR budget follows LDS-implied occupancy (512/(waves/EU));
// holding data in VGPRs starves load pipelining -> latency wall at 1.4 TB/s.
// So: retention goes to LDS (doesn't fight latency hiding) + a SMALL 48-VGPR
// fp16 reg hold; 16 waves/CU with ~80 free VGPRs each restore MLP.
//   strides 0-5  -> fp16 registers (hold16: 4 planes x 6 x uint2 = 48 VGPR)
//   strides 6-9  -> fp16 LDS (131072 B, forces 1 block/CU)
//   strides 10,11,tail -> re-read in phase 3 (~38 MB; often L3-resident)
__global__ __launch_bounds__(NTHR)
void se_fused(const float* __restrict__ x,
              const float* __restrict__ w1,
              const float* __restrict__ b1,
              const float* __restrict__ w2,
              const float* __restrict__ b2,
              float* __restrict__ out,
              float* __restrict__ s_ws) {
    const int bid   = blockIdx.x;
    const int tid   = threadIdx.x;
    const int w     = tid >> 6;
    const int lane  = tid & 63;
    const int batch = bid >> 2;          // 4 blocks per batch
    const int cbase = (bid & 3) * PPB;   // channel base of this block

    __shared__ uint2 lds16[PPB][LSTR][64];   // 131072 B
    __shared__ float sv[CH];                 // 1024 B
    __shared__ float h_lds[RCH];             // 256 B
    __shared__ float g_lds[PPB];             // 256 B  (total 132608 B)

    uint2 hold16[PPW][RSTR];             // 48 VGPR, static-indexed only
    float psum[PPW];

    const f4* __restrict__ xb = (const f4*)x + (size_t)(bid * PPB) * HWF4;

    // ---------------- phase 1: pool + on-chip cache ----------------
    #pragma unroll
    for (int q = 0; q < PPW; ++q) {
        const int pl = w * PPW + q;                    // plane_local 0..63
        const f4* __restrict__ xp = xb + (size_t)pl * HWF4;
        float acc = 0.0f;
        #pragma unroll
        for (int st = 0; st < RSTR; ++st) {            // fp16 regs
            f4 v = xp[st * 64 + lane];
            H4 p;
            p.h[0] = __builtin_amdgcn_cvt_pkrtz(v.x, v.y);
            p.h[1] = __builtin_amdgcn_cvt_pkrtz(v.z, v.w);
            hold16[q][st] = p.u;
            acc += (v.x + v.y) + (v.z + v.w);
        }
        #pragma unroll
        for (int st = RSTR; st < RSTR + LSTR; ++st) {  // fp16 LDS
            f4 v = xp[st * 64 + lane];
            H4 p;
            p.h[0] = __builtin_amdgcn_cvt_pkrtz(v.x, v.y);
            p.h[1] = __builtin_amdgcn_cvt_pkrtz(v.z, v.w);
            lds16[pl][st - RSTR][lane] = p.u;
            acc += (v.x + v.y) + (v.z + v.w);
        }
        #pragma unroll
        for (int st = 10; st < 12; ++st) {             // not held
            f4 v = xp[st * 64 + lane];
            acc += (v.x + v.y) + (v.z + v.w);
        }
        if (lane < 16) {                               // tail: 784 = 12*64+16
            f4 v = xp[768 + lane];
            acc += (v.x + v.y) + (v.z + v.w);
        }
        psum[q] = acc;
    }
    #pragma unroll
    for (int q = 0; q < PPW; ++q) {
        float a = psum[q];
        #pragma unroll
        for (int off = 32; off > 0; off >>= 1)
            a += __shfl_down(a, off, 64);
        if (lane == 0)
            s_ws[bid * PPB + w * PPW + q] = a * (1.0f / (float)HW);
    }

    // ---------------- inline grid barrier ----------------
    __threadfence();                     // release: publish s_ws
    __syncthreads();                     // whole block has arrived
    if (tid == 0) {
        int ticket = __hip_atomic_fetch_add(&g_ctr, 1, __ATOMIC_ACQ_REL,
                                            __HIP_MEMORY_SCOPE_AGENT);
        const int target = ((ticket >> 8) + 1) << 8;   // next multiple of 256
        while (__hip_atomic_load(&g_ctr, __ATOMIC_ACQUIRE,
                                 __HIP_MEMORY_SCOPE_AGENT) < target)
            __builtin_amdgcn_s_sleep(2);
    }
    __syncthreads();
    __threadfence();                     // acquire: see other blocks' s_ws

    // ---------------- phase 2: excite (per block, redundant x4) ----------
    if (tid < CH) sv[tid] = s_ws[batch * CH + tid];
    __syncthreads();
    if (tid < RCH) {
        float acc = b1[tid];
        const float* __restrict__ wr = w1 + tid * CH;
        #pragma unroll 8
        for (int c = 0; c < CH; ++c) acc = fmaf(wr[c], sv[c], acc);
        h_lds[tid] = fmaxf(acc, 0.0f);
    }
    __syncthreads();
    if (tid < PPB) {
        const int c = cbase + tid;
        float acc = b2[c];
        const float* __restrict__ wr = w2 + c * RCH;
        #pragma unroll 8
        for (int r = 0; r < RCH; ++r) acc = fmaf(wr[r], h_lds[r], acc);
        g_lds[tid] = 1.0f / (1.0f + expf(-acc));
    }
    __syncthreads();

    // ---------------- phase 3: scale + store ----------------
    f4* __restrict__ ob = (f4*)out + (size_t)(bid * PPB) * HWF4;
    #pragma unroll
    for (int q = 0; q < PPW; ++q) {
        const int pl = w * PPW + q;
        const f4* __restrict__ xp = xb + (size_t)pl * HWF4;
        f4* __restrict__ op = ob + (size_t)pl * HWF4;
        const float gg = g_lds[pl];

        // issue the HBM re-reads FIRST; held-data stores hide their latency
        f4 r10 = xp[10 * 64 + lane];
        f4 r11 = xp[11 * 64 + lane];

        #pragma unroll
        for (int st = 0; st < RSTR; ++st) {            // fp16 regs
            H4 p; p.u = hold16[q][st];
            f4 v;
            v.x = (float)p.h[0][0]; v.y = (float)p.h[0][1];
            v.z = (float)p.h[1][0]; v.w = (float)p.h[1][1];
            v.x *= gg; v.y *= gg; v.z *= gg; v.w *= gg;
            __builtin_nontemporal_store(v, op + st * 64 + lane);
        }
        #pragma unroll
        for (int st = RSTR; st < RSTR + LSTR; ++st) {  // fp16 LDS
            H4 p; p.u = lds16[pl][st - RSTR][lane];
            f4 v;
            v.x = (float)p.h[0][0]; v.y = (float)p.h[0][1];
            v.z = (float)p.h[1][0]; v.w = (float)p.h[1][1];
            v.x *= gg; v.y *= gg; v.z *= gg; v.w *= gg;
            __builtin_nontemporal_store(v, op + st * 64 + lane);
        }
        r10.x *= gg; r10.y *= gg; r10.z *= gg; r10.w *= gg;
        __builtin_nontemporal_store(r10, op + 10 * 64 + lane);
        r11.x *= gg; r11.y *= gg; r11.z *= gg; r11.w *= gg;
        __builtin_nontemporal_store(r11, op + 11 * 64 + lane);
        if (lane < 16) {
            f4 v = xp[768 + lane];
            v.x *= gg; v.y *= gg; v.z *= gg; v.w *= gg;
            __builtin_nontemporal_store(v, op + 768 + lane);
        }
    }
}

extern "C" void kernel_launch(void* const* d_in, const int* in_sizes, int n_in,
                              void* d_out, int out_size, void* d_ws, size_t ws_size,
                              hipStream_t stream) {
    const float* x  = (const float*)d_in[0];
    const float* w1 = (const float*)d_in[1];
    const float* b1 = (const float*)d_in[2];
    const float* w2 = (const float*)d_in[3];
    const float* b2 = (const float*)d_in[4];
    float* out  = (float*)d_out;
    float* s_ws = (float*)d_ws;          // 16384 floats = 64 KB

    void* args[] = { (void*)&x, (void*)&w1, (void*)&b1, (void*)&w2,
                     (void*)&b2, (void*)&out, (void*)&s_ws };
    hipLaunchCooperativeKernel((const void*)se_fused,
                               dim3(NBLK), dim3(NTHR),
                               args, 0, stream);
}